// Round 10
// baseline (349.304 us; speedup 1.0000x reference)
//
#include <hip/hip_runtime.h>
#include <hip/hip_bf16.h>

// CustomModel_60851096649964: two-stage biased top-k attention, folded weights.
// R10 = R9 with gemm2+gemm3 fused: yS2 = u@(VP1@S2) = u@W35 (precomputed),
// single dual-output GEMM u @ [VP1 | W35] (N=1152, grid 2025 = 8 blk/CU)
// writes both y (ybf) and yS2 (buf1). gemm3 dispatch + 118 MB eliminated;
// gemm2's 1-block/CU latency exposure fixed.

typedef __attribute__((ext_vector_type(4))) float f32x4;
typedef __attribute__((ext_vector_type(8))) short bf16x8v;
typedef __attribute__((ext_vector_type(4))) short short4v;

#define BT_N 2880
#define A_N  10
#define M_N  350
#define BQ_N (BT_N * A_N)   // 28800
#define DIMC 128

static __device__ __forceinline__ short f2b(float x) {
    __hip_bfloat16 b = __float2bfloat16(x);
    return __builtin_bit_cast(short, b);
}
static __device__ __forceinline__ float b2f(short s) {
    unsigned u = ((unsigned)(unsigned short)s) << 16;
    return __builtin_bit_cast(float, u);
}

// ---------------------------------------------------------------------------
// K0: folded per-head matrices (bf16). VP1t now written into B2t rows 0..127;
// additionally emits VP1n[o][d] (transposed copy) for the W35 fold GEMM.
// ---------------------------------------------------------------------------
__global__ __launch_bounds__(256) void precompute_mats(
    const float* __restrict__ Wq, const float* __restrict__ Wk,
    const float* __restrict__ Wv, const float* __restrict__ Wcp,
    const float* __restrict__ Wc, const float* __restrict__ Wsp,
    short* __restrict__ S1t, short* __restrict__ B2t /*rows 0..127 = VP1t*/,
    short* __restrict__ VP1n, short* __restrict__ S2t, short* __restrict__ VP2t)
{
    int gid = blockIdx.x * 256 + threadIdx.x;
    int mat = gid >> 17;
    int idx = gid & 131071;
    float acc = 0.f;
    if (mat == 0) {
        int n = idx >> 7, c = idx & 127;
        int h = n >> 7, d = n & 127;
        #pragma unroll
        for (int t = 0; t < 16; ++t)
            acc += Wq[c * 128 + h * 16 + t] * Wk[d * 128 + h * 16 + t];
        S1t[idx] = f2b(acc * 0.25f);
    } else if (mat == 1) {
        int d = idx >> 10, o = idx & 1023;
        int h = o >> 7, c = o & 127;
        #pragma unroll
        for (int t = 0; t < 16; ++t)
            acc += Wv[c * 128 + h * 16 + t] * Wcp[(h * 16 + t) * 128 + d];
        short v = f2b(acc);
        B2t[idx] = v;                 // VP1t[d][o]
        VP1n[o * 128 + d] = v;        // VP1[o][d]
    } else if (mat == 2) {
        int n = idx >> 7, c = idx & 127;
        int h = n >> 7, d = n & 127;
        #pragma unroll
        for (int t = 0; t < 16; ++t)
            acc += Wc[c * 384 + h * 16 + t] * Wc[d * 384 + 128 + h * 16 + t];
        S2t[idx] = f2b(acc * 0.25f);
    } else {
        int d = idx >> 10, o = idx & 1023;
        int h = o >> 7, c = o & 127;
        #pragma unroll
        for (int t = 0; t < 16; ++t)
            acc += Wc[c * 384 + 256 + h * 16 + t] * Wsp[(h * 16 + t) * 128 + d];
        VP2t[idx] = f2b(acc);
    }
}

// ---------------------------------------------------------------------------
// a_token fp32 -> bf16 (8 elems/thread)
// ---------------------------------------------------------------------------
__global__ __launch_bounds__(256) void conv_bf16(
    const float* __restrict__ in, short* __restrict__ out)
{
    int i = blockIdx.x * 256 + threadIdx.x;   // 0 .. 460799
    f32x4 a = ((const f32x4*)in)[2 * i];
    f32x4 b = ((const f32x4*)in)[2 * i + 1];
    bf16x8v t;
    t[0] = f2b(a.x); t[1] = f2b(a.y); t[2] = f2b(a.z); t[3] = f2b(a.w);
    t[4] = f2b(b.x); t[5] = f2b(b.y); t[6] = f2b(b.z); t[7] = f2b(b.w);
    ((bf16x8v*)out)[i] = t;
}

// ---------------------------------------------------------------------------
// bf16 MFMA GEMM, C[M,N] = A[M,K] @ Bt^T. BM=BN=128, BK=64. (R5 verbatim)
// Also used to fold W35t = S2t @ VP1n  (M=N=1024, K=128).
// ---------------------------------------------------------------------------
template<bool CF32>
__global__ __launch_bounds__(256) void gemm_bt(
    const short* __restrict__ Ap, const short* __restrict__ Bt,
    void* __restrict__ Cp, int M, int N, int K)
{
    __shared__ short As[128][72];
    __shared__ short Bs[128][72];
    const int tid  = threadIdx.x;
    const int bm   = blockIdx.y << 7, bn = blockIdx.x << 7;
    const int wave = tid >> 6, lane = tid & 63;
    const int wm   = (wave >> 1) << 6, wn = (wave & 1) << 6;
    const int row16 = lane & 15, kq = (lane >> 4) << 3;
    f32x4 acc[4][4] = {};

    for (int k0 = 0; k0 < K; k0 += 64) {
        #pragma unroll
        for (int i = 0; i < 4; ++i) {
            int g = (i << 8) + tid;
            int r = g >> 3, c = (g & 7) << 3;
            *(bf16x8v*)&As[r][c] = *(const bf16x8v*)(Ap + (size_t)(bm + r) * K + k0 + c);
        }
        #pragma unroll
        for (int i = 0; i < 4; ++i) {
            int g = (i << 8) + tid;
            int r = g >> 3, c = (g & 7) << 3;
            *(bf16x8v*)&Bs[r][c] = *(const bf16x8v*)(Bt + (size_t)(bn + r) * K + k0 + c);
        }
        __syncthreads();
        #pragma unroll
        for (int kk = 0; kk < 64; kk += 32) {
            bf16x8v afr[4], bfr[4];
            #pragma unroll
            for (int mi = 0; mi < 4; ++mi)
                afr[mi] = *(const bf16x8v*)&As[wm + (mi << 4) + row16][kq + kk];
            #pragma unroll
            for (int ni = 0; ni < 4; ++ni)
                bfr[ni] = *(const bf16x8v*)&Bs[wn + (ni << 4) + row16][kq + kk];
            #pragma unroll
            for (int mi = 0; mi < 4; ++mi)
                #pragma unroll
                for (int ni = 0; ni < 4; ++ni)
                    acc[mi][ni] = __builtin_amdgcn_mfma_f32_16x16x32_bf16(
                        afr[mi], bfr[ni], acc[mi][ni], 0, 0, 0);
        }
        __syncthreads();
    }

    const int col = lane & 15, rb = (lane >> 4) << 2;
    #pragma unroll
    for (int mi = 0; mi < 4; ++mi)
        #pragma unroll
        for (int ni = 0; ni < 4; ++ni)
            #pragma unroll
            for (int r = 0; r < 4; ++r) {
                int rr = bm + wm + (mi << 4) + rb + r;
                int cc = bn + wn + (ni << 4) + col;
                float v = acc[mi][ni][r];
                if (CF32) ((float*)Cp)[(size_t)rr * N + cc] = v;
                else      ((short*)Cp)[(size_t)rr * N + cc] = f2b(v);
            }
}

// ---------------------------------------------------------------------------
// Dual-output GEMM: C = u[M,1024] @ B2t^T (N=1152). Column block 0 -> ybf
// (y, stride 128); blocks 1..8 -> yS2 (stride 1024, cols (bn-1)*128..).
// ---------------------------------------------------------------------------
__global__ __launch_bounds__(256) void gemm_dual(
    const short* __restrict__ Ap, const short* __restrict__ Bt,
    short* __restrict__ Cy, short* __restrict__ Cs, int M, int K)
{
    __shared__ short As[128][72];
    __shared__ short Bs[128][72];
    const int tid  = threadIdx.x;
    const int bm   = blockIdx.y << 7, bn = blockIdx.x << 7;
    const int wave = tid >> 6, lane = tid & 63;
    const int wm   = (wave >> 1) << 6, wn = (wave & 1) << 6;
    const int row16 = lane & 15, kq = (lane >> 4) << 3;
    f32x4 acc[4][4] = {};

    for (int k0 = 0; k0 < K; k0 += 64) {
        #pragma unroll
        for (int i = 0; i < 4; ++i) {
            int g = (i << 8) + tid;
            int r = g >> 3, c = (g & 7) << 3;
            *(bf16x8v*)&As[r][c] = *(const bf16x8v*)(Ap + (size_t)(bm + r) * K + k0 + c);
        }
        #pragma unroll
        for (int i = 0; i < 4; ++i) {
            int g = (i << 8) + tid;
            int r = g >> 3, c = (g & 7) << 3;
            *(bf16x8v*)&Bs[r][c] = *(const bf16x8v*)(Bt + (size_t)(bn + r) * K + k0 + c);
        }
        __syncthreads();
        #pragma unroll
        for (int kk = 0; kk < 64; kk += 32) {
            bf16x8v afr[4], bfr[4];
            #pragma unroll
            for (int mi = 0; mi < 4; ++mi)
                afr[mi] = *(const bf16x8v*)&As[wm + (mi << 4) + row16][kq + kk];
            #pragma unroll
            for (int ni = 0; ni < 4; ++ni)
                bfr[ni] = *(const bf16x8v*)&Bs[wn + (ni << 4) + row16][kq + kk];
            #pragma unroll
            for (int mi = 0; mi < 4; ++mi)
                #pragma unroll
                for (int ni = 0; ni < 4; ++ni)
                    acc[mi][ni] = __builtin_amdgcn_mfma_f32_16x16x32_bf16(
                        afr[mi], bfr[ni], acc[mi][ni], 0, 0, 0);
        }
        __syncthreads();
    }

    const int col = lane & 15, rb = (lane >> 4) << 2;
    #pragma unroll
    for (int mi = 0; mi < 4; ++mi)
        #pragma unroll
        for (int ni = 0; ni < 4; ++ni)
            #pragma unroll
            for (int r = 0; r < 4; ++r) {
                int rr = bm + wm + (mi << 4) + rb + r;
                int cl = wn + (ni << 4) + col;      // 0..127 within block col
                short v = f2b(acc[mi][ni][r]);
                if (bn == 0) Cy[(size_t)rr * 128 + cl] = v;
                else         Cs[(size_t)rr * 1024 + (bn - 128) + cl] = v;
            }
}

// ---------------------------------------------------------------------------
// Cross attention v3 (R9 verbatim): MFMA score, bf16 mrows, XCD-swizzled.
// ---------------------------------------------------------------------------
__global__ __launch_bounds__(256) void attn_cross(
    const float* __restrict__ m_token, const short* __restrict__ qS,
    const float* __restrict__ pe, const int* __restrict__ rel,
    short* __restrict__ u)
{
    __shared__ short mrows[32][136];
    __shared__ short qsr[16][136];
    __shared__ float sc[32][17];
    __shared__ float wts[8][33];
    __shared__ float peL[256];
    __shared__ int   selk[32];

    const int phys = blockIdx.x;
    const int b    = (phys & 7) * 360 + (phys >> 3) / A_N;
    const int q    = (phys >> 3) % A_N;
    const int bq   = b * A_N + q;
    const int tid  = threadIdx.x;
    const int wave = tid >> 6, lane = tid & 63;
    const int row16 = lane & 15, kq8 = (lane >> 4) << 3;

    const int* relrow = rel + (size_t)bq * M_N;
    for (int k = tid; k < M_N; k += 256) {
        int r = relrow[k];
        if (r >= 0) selk[r] = k;
    }
    if (tid < 128) {
        int h = tid >> 4, c8 = (tid & 15) << 3;
        *(bf16x8v*)&qsr[h][c8] = *(const bf16x8v*)(qS + (size_t)bq * 1024 + h * 128 + c8);
    }
    for (int g = tid; g < 1088; g += 256) ((short*)qsr)[1088 + g] = 0;
    peL[tid] = pe[(size_t)bq * 256 + tid];
    __syncthreads();

    {
        int r = tid >> 3, c16 = (tid & 7) << 4;
        const float* src = m_token + ((size_t)b * M_N + selk[r]) * DIMC + c16;
        f32x4 v0 = *(const f32x4*)(src);
        f32x4 v1 = *(const f32x4*)(src + 4);
        f32x4 v2 = *(const f32x4*)(src + 8);
        f32x4 v3 = *(const f32x4*)(src + 12);
        bf16x8v t0, t1;
        t0[0] = f2b(v0.x); t0[1] = f2b(v0.y); t0[2] = f2b(v0.z); t0[3] = f2b(v0.w);
        t0[4] = f2b(v1.x); t0[5] = f2b(v1.y); t0[6] = f2b(v1.z); t0[7] = f2b(v1.w);
        t1[0] = f2b(v2.x); t1[1] = f2b(v2.y); t1[2] = f2b(v2.z); t1[3] = f2b(v2.w);
        t1[4] = f2b(v3.x); t1[5] = f2b(v3.y); t1[6] = f2b(v3.z); t1[7] = f2b(v3.w);
        *(bf16x8v*)&mrows[r][c16]     = t0;
        *(bf16x8v*)&mrows[r][c16 + 8] = t1;
    }
    __syncthreads();

    if (wave < 2) {
        f32x4 acc = {0.f, 0.f, 0.f, 0.f};
        #pragma unroll
        for (int kc = 0; kc < 4; ++kc) {
            bf16x8v a  = *(const bf16x8v*)&mrows[(wave << 4) + row16][(kc << 5) + kq8];
            bf16x8v bb = *(const bf16x8v*)&qsr[row16][(kc << 5) + kq8];
            acc = __builtin_amdgcn_mfma_f32_16x16x32_bf16(a, bb, acc, 0, 0, 0);
        }
        const int rb4 = (lane >> 4) << 2;
        #pragma unroll
        for (int r = 0; r < 4; ++r)
            sc[(wave << 4) + rb4 + r][row16] = acc[r];
    }
    __syncthreads();

    {
        const int h = tid >> 5, r = tid & 31;
        float s = sc[r][h] + peL[r * 8 + h];
        float mx = s;
        #pragma unroll
        for (int off = 16; off; off >>= 1) mx = fmaxf(mx, __shfl_xor(mx, off, 32));
        float e = __expf(s - mx);
        float su = e;
        #pragma unroll
        for (int off = 16; off; off >>= 1) su += __shfl_xor(su, off, 32);
        wts[h][r] = e / su;
    }
    __syncthreads();

    {
        const int h = tid >> 5, d0 = (tid << 2) & 127;
        f32x4 acc = {0.f, 0.f, 0.f, 0.f};
        #pragma unroll
        for (int r = 0; r < 32; ++r) {
            float w = wts[h][r];
            short4v mv = *(const short4v*)&mrows[r][d0];
            acc.x += w * b2f(mv.x);
            acc.y += w * b2f(mv.y);
            acc.z += w * b2f(mv.z);
            acc.w += w * b2f(mv.w);
        }
        short4v t;
        t.x = f2b(acc.x); t.y = f2b(acc.y); t.z = f2b(acc.z); t.w = f2b(acc.w);
        *(short4v*)(u + (size_t)bq * 1024 + (tid << 2)) = t;
    }
}

// ---------------------------------------------------------------------------
// Self attention: per (b,q) block (R5 verbatim).
// ---------------------------------------------------------------------------
__global__ __launch_bounds__(256) void attn_self(
    const short* __restrict__ ybf, const short* __restrict__ yS2,
    const float* __restrict__ pe, const int* __restrict__ rel,
    short* __restrict__ u2)
{
    __shared__ float yrows[3][132];
    __shared__ float ysr[1024];
    __shared__ int   selk[3];
    __shared__ float sw[8][3];
    const int bq = blockIdx.x;
    const int b  = bq / A_N;
    const int tid = threadIdx.x;

    if (tid < A_N) {
        int r = rel[(size_t)bq * A_N + tid];
        if (r >= 0) selk[r] = tid;
    }
    {
        short4v v = ((const short4v*)(yS2 + (size_t)bq * 1024))[tid];
        ysr[(tid << 2) + 0] = b2f(v.x);
        ysr[(tid << 2) + 1] = b2f(v.y);
        ysr[(tid << 2) + 2] = b2f(v.z);
        ysr[(tid << 2) + 3] = b2f(v.w);
    }
    __syncthreads();
    if (tid < 48) {
        int r = tid >> 4, c = (tid & 15) << 3;
        bf16x8v v = *(const bf16x8v*)(ybf + ((size_t)b * A_N + selk[r]) * DIMC + c);
        #pragma unroll
        for (int j = 0; j < 8; ++j) yrows[r][c + j] = b2f(v[j]);
    }
    __syncthreads();
    if (tid < 24) {
        int h = tid / 3, r = tid - h * 3;
        const float* qh = ysr + (h << 7);
        f32x4 p = {0.f, 0.f, 0.f, 0.f};
        #pragma unroll
        for (int d = 0; d < DIMC; d += 4)
            p += *(const f32x4*)(qh + d) * *(const f32x4*)&yrows[r][d];
        sw[h][r] = p.x + p.y + p.z + p.w + pe[((size_t)bq * 3 + r) * 8 + h];
    }
    __syncthreads();
    if (tid < 8) {
        float s0 = sw[tid][0], s1 = sw[tid][1], s2 = sw[tid][2];
        float mx = fmaxf(s0, fmaxf(s1, s2));
        float e0 = __expf(s0 - mx), e1 = __expf(s1 - mx), e2 = __expf(s2 - mx);
        float inv = 1.f / (e0 + e1 + e2);
        sw[tid][0] = e0 * inv; sw[tid][1] = e1 * inv; sw[tid][2] = e2 * inv;
    }
    __syncthreads();
    {
        const int h = tid >> 5, d0 = (tid << 2) & 127;
        f32x4 acc = sw[h][0] * *(const f32x4*)&yrows[0][d0]
                  + sw[h][1] * *(const f32x4*)&yrows[1][d0]
                  + sw[h][2] * *(const f32x4*)&yrows[2][d0];
        short4v t;
        t.x = f2b(acc.x); t.y = f2b(acc.y); t.z = f2b(acc.z); t.w = f2b(acc.w);
        *(short4v*)(u2 + (size_t)bq * 1024 + (tid << 2)) = t;
    }
}

// ---------------------------------------------------------------------------
extern "C" void kernel_launch(void* const* d_in, const int* in_sizes, int n_in,
                              void* d_out, int out_size, void* d_ws, size_t ws_size,
                              hipStream_t stream)
{
    const float* a_token = (const float*)d_in[0];
    const float* m_token = (const float*)d_in[1];
    const float* a2m_pe  = (const float*)d_in[2];
    const float* a_pe    = (const float*)d_in[3];
    const float* Wq      = (const float*)d_in[4];
    const float* Wk      = (const float*)d_in[5];
    const float* Wv      = (const float*)d_in[6];
    const float* Wcp     = (const float*)d_in[7];
    const float* Wc      = (const float*)d_in[8];
    const float* Wsp     = (const float*)d_in[9];
    const int*   a2m_rel = (const int*)d_in[10];
    const int*   a_rel   = (const int*)d_in[11];

    char* ws = (char*)d_ws;                                    // ws ~2 GB (poison fill size)
    short* S1t  = (short*)(ws + 0);
    short* VP1n = (short*)(ws + 262144);                       // VP1 row-major [1024][128]
    short* S2t  = (short*)(ws + 524288);
    short* VP2t = (short*)(ws + 786432);
    short* buf1 = (short*)(ws + 1048576);                      // qS, later yS2  [28800][1024]
    short* buf2 = (short*)(ws + 1048576 + 58982400ull);        // u,  later u2   [28800][1024]
    short* ybf  = (short*)(ws + 1048576 + 2ull * 58982400ull); // y bf16 [28800][128]
    short* abf  = (short*)(ws + 1048576 + 2ull * 58982400ull + 7372800ull); // a_token bf16
    short* B2t  = (short*)(ws + 133758976ull);                 // [1152][1024]: VP1t | W35t
    float* outp = (float*)d_out;

    precompute_mats<<<dim3(2048), dim3(256), 0, stream>>>(
        Wq, Wk, Wv, Wcp, Wc, Wsp, S1t, B2t, VP1n, S2t, VP2t);

    // W35t = S2t @ VP1n   [1024,1024], K=128  -> B2t rows 128..1151
    gemm_bt<false><<<dim3(8, 8), dim3(256), 0, stream>>>(
        S2t, VP1n, (void*)(B2t + 131072), 1024, 1024, 128);

    conv_bf16<<<dim3(1800), dim3(256), 0, stream>>>(a_token, abf);

    // qS = a @ S1   [28800,1024], K=128
    gemm_bt<false><<<dim3(8, 225), dim3(256), 0, stream>>>(
        abf, S1t, (void*)buf1, BQ_N, 1024, 128);

    attn_cross<<<dim3(BQ_N), dim3(256), 0, stream>>>(
        m_token, buf1, a2m_pe, a2m_rel, buf2);

    // [y | yS2] = u @ [VP1 | W35]   (N=1152, grid 2025 = 8 blk/CU)
    gemm_dual<<<dim3(9, 225), dim3(256), 0, stream>>>(
        buf2, B2t, ybf, buf1, BQ_N, 1024);

    attn_self<<<dim3(BQ_N), dim3(256), 0, stream>>>(
        ybf, buf1, a_pe, a_rel, buf2);

    // out = u2 @ VP2   [28800,128], K=1024, fp32 -> d_out
    gemm_bt<true><<<dim3(1, 225), dim3(256), 0, stream>>>(
        buf2, VP2t, (void*)outp, BQ_N, 128, 1024);
}

// Round 11
// 287.444 us; speedup vs baseline: 1.2152x; 1.2152x over previous
//
#include <hip/hip_runtime.h>
#include <hip/hip_bf16.h>

// CustomModel_60851096649964: two-stage biased top-k attention, folded weights.
// R11 = R9 with the tail {gemm3, attn_self, gemm4} replaced by:
//   gemm3z: [yS2 | Z] = ybf @ [S2 | VP2z]  (K=128, N=2048, A is L3-resident)
//   attn_self2: out[q,d] = sum_h sum_r w * Z[k_r, h*128+d]  (writes fp32 out)
// Deletes gemm4 (latency-naked 1-blk/CU dispatch) and the u2 round-trip.
// R10 lesson: never fold through a K-expanding projection; wide-N fusion only
// when A is cache-resident (ybf = 7.4 MB, L3-fit; R10's u = 59 MB was not).

typedef __attribute__((ext_vector_type(4))) float f32x4;
typedef __attribute__((ext_vector_type(8))) short bf16x8v;
typedef __attribute__((ext_vector_type(4))) short short4v;

#define BT_N 2880
#define A_N  10
#define M_N  350
#define BQ_N (BT_N * A_N)   // 28800
#define DIMC 128

static __device__ __forceinline__ short f2b(float x) {
    __hip_bfloat16 b = __float2bfloat16(x);
    return __builtin_bit_cast(short, b);
}
static __device__ __forceinline__ float b2f(short s) {
    unsigned u = ((unsigned)(unsigned short)s) << 16;
    return __builtin_bit_cast(float, u);
}

// ---------------------------------------------------------------------------
// K0: folded per-head matrices (bf16). mat 3 now emits VP2z[h*128+d][c]
// (B^T layout for the K=128 Z-GEMM), replacing VP2t.
// ---------------------------------------------------------------------------
__global__ __launch_bounds__(256) void precompute_mats(
    const float* __restrict__ Wq, const float* __restrict__ Wk,
    const float* __restrict__ Wv, const float* __restrict__ Wcp,
    const float* __restrict__ Wc, const float* __restrict__ Wsp,
    short* __restrict__ S1t, short* __restrict__ VP1t,
    short* __restrict__ S2t, short* __restrict__ VP2z)
{
    int gid = blockIdx.x * 256 + threadIdx.x;
    int mat = gid >> 17;
    int idx = gid & 131071;
    float acc = 0.f;
    if (mat == 0) {
        int n = idx >> 7, c = idx & 127;
        int h = n >> 7, d = n & 127;
        #pragma unroll
        for (int t = 0; t < 16; ++t)
            acc += Wq[c * 128 + h * 16 + t] * Wk[d * 128 + h * 16 + t];
        S1t[idx] = f2b(acc * 0.25f);
    } else if (mat == 1) {
        int d = idx >> 10, o = idx & 1023;
        int h = o >> 7, c = o & 127;
        #pragma unroll
        for (int t = 0; t < 16; ++t)
            acc += Wv[c * 128 + h * 16 + t] * Wcp[(h * 16 + t) * 128 + d];
        VP1t[idx] = f2b(acc);
    } else if (mat == 2) {
        int n = idx >> 7, c = idx & 127;
        int h = n >> 7, d = n & 127;
        #pragma unroll
        for (int t = 0; t < 16; ++t)
            acc += Wc[c * 384 + h * 16 + t] * Wc[d * 384 + 128 + h * 16 + t];
        S2t[idx] = f2b(acc * 0.25f);
    } else {
        // VP2z[n=h*128+d][c] = sum_t Wc[c][256+h16+t] * Wsp[h16+t][d]
        int n = idx >> 7, c = idx & 127;
        int h = n >> 7, d = n & 127;
        #pragma unroll
        for (int t = 0; t < 16; ++t)
            acc += Wc[c * 384 + 256 + h * 16 + t] * Wsp[(h * 16 + t) * 128 + d];
        VP2z[idx] = f2b(acc);
    }
}

// ---------------------------------------------------------------------------
// a_token fp32 -> bf16 (8 elems/thread)
// ---------------------------------------------------------------------------
__global__ __launch_bounds__(256) void conv_bf16(
    const float* __restrict__ in, short* __restrict__ out)
{
    int i = blockIdx.x * 256 + threadIdx.x;   // 0 .. 460799
    f32x4 a = ((const f32x4*)in)[2 * i];
    f32x4 b = ((const f32x4*)in)[2 * i + 1];
    bf16x8v t;
    t[0] = f2b(a.x); t[1] = f2b(a.y); t[2] = f2b(a.z); t[3] = f2b(a.w);
    t[4] = f2b(b.x); t[5] = f2b(b.y); t[6] = f2b(b.z); t[7] = f2b(b.w);
    ((bf16x8v*)out)[i] = t;
}

// ---------------------------------------------------------------------------
// bf16 MFMA GEMM, C[M,N] = A[M,K] @ Bt^T. BM=BN=128, BK=64. (R5/R9 verbatim)
// ---------------------------------------------------------------------------
template<bool CF32>
__global__ __launch_bounds__(256) void gemm_bt(
    const short* __restrict__ Ap, const short* __restrict__ Bt,
    void* __restrict__ Cp, int M, int N, int K)
{
    __shared__ short As[128][72];
    __shared__ short Bs[128][72];
    const int tid  = threadIdx.x;
    const int bm   = blockIdx.y << 7, bn = blockIdx.x << 7;
    const int wave = tid >> 6, lane = tid & 63;
    const int wm   = (wave >> 1) << 6, wn = (wave & 1) << 6;
    const int row16 = lane & 15, kq = (lane >> 4) << 3;
    f32x4 acc[4][4] = {};

    for (int k0 = 0; k0 < K; k0 += 64) {
        #pragma unroll
        for (int i = 0; i < 4; ++i) {
            int g = (i << 8) + tid;
            int r = g >> 3, c = (g & 7) << 3;
            *(bf16x8v*)&As[r][c] = *(const bf16x8v*)(Ap + (size_t)(bm + r) * K + k0 + c);
        }
        #pragma unroll
        for (int i = 0; i < 4; ++i) {
            int g = (i << 8) + tid;
            int r = g >> 3, c = (g & 7) << 3;
            *(bf16x8v*)&Bs[r][c] = *(const bf16x8v*)(Bt + (size_t)(bn + r) * K + k0 + c);
        }
        __syncthreads();
        #pragma unroll
        for (int kk = 0; kk < 64; kk += 32) {
            bf16x8v afr[4], bfr[4];
            #pragma unroll
            for (int mi = 0; mi < 4; ++mi)
                afr[mi] = *(const bf16x8v*)&As[wm + (mi << 4) + row16][kq + kk];
            #pragma unroll
            for (int ni = 0; ni < 4; ++ni)
                bfr[ni] = *(const bf16x8v*)&Bs[wn + (ni << 4) + row16][kq + kk];
            #pragma unroll
            for (int mi = 0; mi < 4; ++mi)
                #pragma unroll
                for (int ni = 0; ni < 4; ++ni)
                    acc[mi][ni] = __builtin_amdgcn_mfma_f32_16x16x32_bf16(
                        afr[mi], bfr[ni], acc[mi][ni], 0, 0, 0);
        }
        __syncthreads();
    }

    const int col = lane & 15, rb = (lane >> 4) << 2;
    #pragma unroll
    for (int mi = 0; mi < 4; ++mi)
        #pragma unroll
        for (int ni = 0; ni < 4; ++ni)
            #pragma unroll
            for (int r = 0; r < 4; ++r) {
                int rr = bm + wm + (mi << 4) + rb + r;
                int cc = bn + wn + (ni << 4) + col;
                float v = acc[mi][ni][r];
                if (CF32) ((float*)Cp)[(size_t)rr * N + cc] = v;
                else      ((short*)Cp)[(size_t)rr * N + cc] = f2b(v);
            }
}

// ---------------------------------------------------------------------------
// gemm3z: [yS2 | Z] = ybf[M,128] @ [S2t ; VP2z]^T  (N=2048, K=128).
// Column blocks 0..7 -> Cs (yS2), 8..15 -> Cz (Z). A is 7.4 MB, L3-resident,
// so 16x A-re-reads stay on-die (the R10 failure mode does not apply).
// ---------------------------------------------------------------------------
__global__ __launch_bounds__(256) void gemm3z(
    const short* __restrict__ Ap, const short* __restrict__ Bt,
    short* __restrict__ Cs, short* __restrict__ Cz, int M)
{
    __shared__ short As[128][72];
    __shared__ short Bs[128][72];
    const int tid  = threadIdx.x;
    const int bm   = blockIdx.y << 7, bn = blockIdx.x << 7;
    const int wave = tid >> 6, lane = tid & 63;
    const int wm   = (wave >> 1) << 6, wn = (wave & 1) << 6;
    const int row16 = lane & 15, kq = (lane >> 4) << 3;
    f32x4 acc[4][4] = {};

    for (int k0 = 0; k0 < 128; k0 += 64) {
        #pragma unroll
        for (int i = 0; i < 4; ++i) {
            int g = (i << 8) + tid;
            int r = g >> 3, c = (g & 7) << 3;
            *(bf16x8v*)&As[r][c] = *(const bf16x8v*)(Ap + (size_t)(bm + r) * 128 + k0 + c);
        }
        #pragma unroll
        for (int i = 0; i < 4; ++i) {
            int g = (i << 8) + tid;
            int r = g >> 3, c = (g & 7) << 3;
            *(bf16x8v*)&Bs[r][c] = *(const bf16x8v*)(Bt + (size_t)(bn + r) * 128 + k0 + c);
        }
        __syncthreads();
        #pragma unroll
        for (int kk = 0; kk < 64; kk += 32) {
            bf16x8v afr[4], bfr[4];
            #pragma unroll
            for (int mi = 0; mi < 4; ++mi)
                afr[mi] = *(const bf16x8v*)&As[wm + (mi << 4) + row16][kq + kk];
            #pragma unroll
            for (int ni = 0; ni < 4; ++ni)
                bfr[ni] = *(const bf16x8v*)&Bs[wn + (ni << 4) + row16][kq + kk];
            #pragma unroll
            for (int mi = 0; mi < 4; ++mi)
                #pragma unroll
                for (int ni = 0; ni < 4; ++ni)
                    acc[mi][ni] = __builtin_amdgcn_mfma_f32_16x16x32_bf16(
                        afr[mi], bfr[ni], acc[mi][ni], 0, 0, 0);
        }
        __syncthreads();
    }

    const int col = lane & 15, rb = (lane >> 4) << 2;
    #pragma unroll
    for (int mi = 0; mi < 4; ++mi)
        #pragma unroll
        for (int ni = 0; ni < 4; ++ni)
            #pragma unroll
            for (int r = 0; r < 4; ++r) {
                int rr = bm + wm + (mi << 4) + rb + r;
                int nn = bn + wn + (ni << 4) + col;   // 0..2047, uniform side per block
                short v = f2b(acc[mi][ni][r]);
                if (nn < 1024) Cs[(size_t)rr * 1024 + nn] = v;
                else           Cz[(size_t)rr * 1024 + nn - 1024] = v;
            }
}

// ---------------------------------------------------------------------------
// Cross attention v3 (R9 verbatim): MFMA score, bf16 mrows, XCD-swizzled.
// ---------------------------------------------------------------------------
__global__ __launch_bounds__(256) void attn_cross(
    const float* __restrict__ m_token, const short* __restrict__ qS,
    const float* __restrict__ pe, const int* __restrict__ rel,
    short* __restrict__ u)
{
    __shared__ short mrows[32][136];
    __shared__ short qsr[16][136];
    __shared__ float sc[32][17];
    __shared__ float wts[8][33];
    __shared__ float peL[256];
    __shared__ int   selk[32];

    const int phys = blockIdx.x;
    const int b    = (phys & 7) * 360 + (phys >> 3) / A_N;
    const int q    = (phys >> 3) % A_N;
    const int bq   = b * A_N + q;
    const int tid  = threadIdx.x;
    const int wave = tid >> 6, lane = tid & 63;
    const int row16 = lane & 15, kq8 = (lane >> 4) << 3;

    const int* relrow = rel + (size_t)bq * M_N;
    for (int k = tid; k < M_N; k += 256) {
        int r = relrow[k];
        if (r >= 0) selk[r] = k;
    }
    if (tid < 128) {
        int h = tid >> 4, c8 = (tid & 15) << 3;
        *(bf16x8v*)&qsr[h][c8] = *(const bf16x8v*)(qS + (size_t)bq * 1024 + h * 128 + c8);
    }
    for (int g = tid; g < 1088; g += 256) ((short*)qsr)[1088 + g] = 0;
    peL[tid] = pe[(size_t)bq * 256 + tid];
    __syncthreads();

    {
        int r = tid >> 3, c16 = (tid & 7) << 4;
        const float* src = m_token + ((size_t)b * M_N + selk[r]) * DIMC + c16;
        f32x4 v0 = *(const f32x4*)(src);
        f32x4 v1 = *(const f32x4*)(src + 4);
        f32x4 v2 = *(const f32x4*)(src + 8);
        f32x4 v3 = *(const f32x4*)(src + 12);
        bf16x8v t0, t1;
        t0[0] = f2b(v0.x); t0[1] = f2b(v0.y); t0[2] = f2b(v0.z); t0[3] = f2b(v0.w);
        t0[4] = f2b(v1.x); t0[5] = f2b(v1.y); t0[6] = f2b(v1.z); t0[7] = f2b(v1.w);
        t1[0] = f2b(v2.x); t1[1] = f2b(v2.y); t1[2] = f2b(v2.z); t1[3] = f2b(v2.w);
        t1[4] = f2b(v3.x); t1[5] = f2b(v3.y); t1[6] = f2b(v3.z); t1[7] = f2b(v3.w);
        *(bf16x8v*)&mrows[r][c16]     = t0;
        *(bf16x8v*)&mrows[r][c16 + 8] = t1;
    }
    __syncthreads();

    if (wave < 2) {
        f32x4 acc = {0.f, 0.f, 0.f, 0.f};
        #pragma unroll
        for (int kc = 0; kc < 4; ++kc) {
            bf16x8v a  = *(const bf16x8v*)&mrows[(wave << 4) + row16][(kc << 5) + kq8];
            bf16x8v bb = *(const bf16x8v*)&qsr[row16][(kc << 5) + kq8];
            acc = __builtin_amdgcn_mfma_f32_16x16x32_bf16(a, bb, acc, 0, 0, 0);
        }
        const int rb4 = (lane >> 4) << 2;
        #pragma unroll
        for (int r = 0; r < 4; ++r)
            sc[(wave << 4) + rb4 + r][row16] = acc[r];
    }
    __syncthreads();

    {
        const int h = tid >> 5, r = tid & 31;
        float s = sc[r][h] + peL[r * 8 + h];
        float mx = s;
        #pragma unroll
        for (int off = 16; off; off >>= 1) mx = fmaxf(mx, __shfl_xor(mx, off, 32));
        float e = __expf(s - mx);
        float su = e;
        #pragma unroll
        for (int off = 16; off; off >>= 1) su += __shfl_xor(su, off, 32);
        wts[h][r] = e / su;
    }
    __syncthreads();

    {
        const int h = tid >> 5, d0 = (tid << 2) & 127;
        f32x4 acc = {0.f, 0.f, 0.f, 0.f};
        #pragma unroll
        for (int r = 0; r < 32; ++r) {
            float w = wts[h][r];
            short4v mv = *(const short4v*)&mrows[r][d0];
            acc.x += w * b2f(mv.x);
            acc.y += w * b2f(mv.y);
            acc.z += w * b2f(mv.z);
            acc.w += w * b2f(mv.w);
        }
        short4v t;
        t.x = f2b(acc.x); t.y = f2b(acc.y); t.z = f2b(acc.z); t.w = f2b(acc.w);
        *(short4v*)(u + (size_t)bq * 1024 + (tid << 2)) = t;
    }
}

// ---------------------------------------------------------------------------
// Self attention v2: per (b,q) block, XCD-swizzled. Reads yS2 (q-side), y
// (3 selected k rows for scores), Z (3 selected rows); combines Z directly
// into out fp32 (gemm4 folded away).
// ---------------------------------------------------------------------------
__global__ __launch_bounds__(256) void attn_self2(
    const short* __restrict__ ybf, const short* __restrict__ yS2,
    const short* __restrict__ Zb, const float* __restrict__ pe,
    const int* __restrict__ rel, float* __restrict__ outp)
{
    __shared__ float yrows[3][132];
    __shared__ float ysr[1024];
    __shared__ short Zl[3][1024];
    __shared__ int   selk[3];
    __shared__ float sw[8][3];
    const int phys = blockIdx.x;
    const int b    = (phys & 7) * 360 + (phys >> 3) / A_N;
    const int q    = (phys >> 3) % A_N;
    const int bq   = b * A_N + q;
    const int tid  = threadIdx.x;

    if (tid < A_N) {
        int r = rel[(size_t)bq * A_N + tid];
        if (r >= 0) selk[r] = tid;
    }
    {
        short4v v = ((const short4v*)(yS2 + (size_t)bq * 1024))[tid];
        ysr[(tid << 2) + 0] = b2f(v.x);
        ysr[(tid << 2) + 1] = b2f(v.y);
        ysr[(tid << 2) + 2] = b2f(v.z);
        ysr[(tid << 2) + 3] = b2f(v.w);
    }
    __syncthreads();
    // y rows (scores) + Z rows (combine) for the 3 selected keys
    if (tid < 48) {
        int r = tid >> 4, c = (tid & 15) << 3;
        bf16x8v v = *(const bf16x8v*)(ybf + ((size_t)b * A_N + selk[r]) * DIMC + c);
        #pragma unroll
        for (int j = 0; j < 8; ++j) yrows[r][c + j] = b2f(v[j]);
    }
    for (int g = tid; g < 384; g += 256) {
        int r = g >> 7, c8 = (g & 127) << 3;
        *(bf16x8v*)&Zl[r][c8] =
            *(const bf16x8v*)(Zb + ((size_t)b * A_N + selk[r]) * 1024 + c8);
    }
    if (tid < 24) {
        // scores need yrows: placed after, but same barrier region -- guard:
    }
    __syncthreads();
    if (tid < 24) {
        int h = tid / 3, r = tid - h * 3;
        const float* qh = ysr + (h << 7);
        f32x4 p = {0.f, 0.f, 0.f, 0.f};
        #pragma unroll
        for (int d = 0; d < DIMC; d += 4)
            p += *(const f32x4*)(qh + d) * *(const f32x4*)&yrows[r][d];
        sw[h][r] = p.x + p.y + p.z + p.w + pe[((size_t)bq * 3 + r) * 8 + h];
    }
    __syncthreads();
    if (tid < 8) {
        float s0 = sw[tid][0], s1 = sw[tid][1], s2 = sw[tid][2];
        float mx = fmaxf(s0, fmaxf(s1, s2));
        float e0 = __expf(s0 - mx), e1 = __expf(s1 - mx), e2 = __expf(s2 - mx);
        float inv = 1.f / (e0 + e1 + e2);
        sw[tid][0] = e0 * inv; sw[tid][1] = e1 * inv; sw[tid][2] = e2 * inv;
    }
    __syncthreads();
    if (tid < 128) {
        const int d = tid;
        float acc = 0.f;
        #pragma unroll
        for (int h = 0; h < 8; ++h) {
            float w0 = sw[h][0], w1 = sw[h][1], w2 = sw[h][2];
            acc += w0 * b2f(Zl[0][(h << 7) + d])
                 + w1 * b2f(Zl[1][(h << 7) + d])
                 + w2 * b2f(Zl[2][(h << 7) + d]);
        }
        outp[(size_t)bq * 128 + d] = acc;
    }
}

// ---------------------------------------------------------------------------
extern "C" void kernel_launch(void* const* d_in, const int* in_sizes, int n_in,
                              void* d_out, int out_size, void* d_ws, size_t ws_size,
                              hipStream_t stream)
{
    const float* a_token = (const float*)d_in[0];
    const float* m_token = (const float*)d_in[1];
    const float* a2m_pe  = (const float*)d_in[2];
    const float* a_pe    = (const float*)d_in[3];
    const float* Wq      = (const float*)d_in[4];
    const float* Wk      = (const float*)d_in[5];
    const float* Wv      = (const float*)d_in[6];
    const float* Wcp     = (const float*)d_in[7];
    const float* Wc      = (const float*)d_in[8];
    const float* Wsp     = (const float*)d_in[9];
    const int*   a2m_rel = (const int*)d_in[10];
    const int*   a_rel   = (const int*)d_in[11];

    char* ws = (char*)d_ws;
    short* S1t  = (short*)(ws + 0);
    short* VP1t = (short*)(ws + 262144);
    short* S2t  = (short*)(ws + 524288);       // rows 0..1023 of gemm3z B
    short* VP2z = (short*)(ws + 786432);       // rows 1024..2047 (contiguous)
    short* buf1 = (short*)(ws + 1048576);                      // qS, later yS2
    short* buf2 = (short*)(ws + 1048576 + 58982400ull);        // u
    short* ybf  = (short*)(ws + 1048576 + 2ull * 58982400ull); // y bf16
    short* abf  = (short*)(ws + 126386176ull);                 // a_token bf16
    short* zbuf = (short*)(ws + 133758976ull);                 // Z [28800][1024]
    float* outp = (float*)d_out;

    precompute_mats<<<dim3(2048), dim3(256), 0, stream>>>(
        Wq, Wk, Wv, Wcp, Wc, Wsp, S1t, VP1t, S2t, VP2z);

    conv_bf16<<<dim3(1800), dim3(256), 0, stream>>>(a_token, abf);

    // qS = a @ S1   [28800,1024], K=128
    gemm_bt<false><<<dim3(8, 225), dim3(256), 0, stream>>>(
        abf, S1t, (void*)buf1, BQ_N, 1024, 128);

    attn_cross<<<dim3(BQ_N), dim3(256), 0, stream>>>(
        m_token, buf1, a2m_pe, a2m_rel, buf2);

    // y = u @ VP1   [28800,128], K=1024
    gemm_bt<false><<<dim3(1, 225), dim3(256), 0, stream>>>(
        buf2, VP1t, (void*)ybf, BQ_N, 128, 1024);

    // [yS2 | Z] = ybf @ [S2 | VP2z]   (N=2048, K=128, grid 3600)
    gemm3z<<<dim3(16, 225), dim3(256), 0, stream>>>(
        ybf, S2t, buf1, zbuf, BQ_N);

    attn_self2<<<dim3(BQ_N), dim3(256), 0, stream>>>(
        ybf, buf1, zbuf, a_pe, a_rel, outp);
}